// Round 3
// baseline (296.224 us; speedup 1.0000x reference)
//
#include <hip/hip_runtime.h>
#include <math.h>

#define Bn 4096
#define Tn 512
#define Vn 57
#define En 20
#define Hn 128
#define On 18
#define ROWS 8           // batch rows per block (half-filled MFMA N: latency > thpt)
#define NTHR 512         // 8 waves per block
#define NBLK (Bn / ROWS) // 512 blocks -> 2 independent blocks/CU (TLP across barriers)
#define KC 5             // A K-chunks: 4x32 (W_hh) + 1x32 (W_ih 20 + bias 1 + 11 zero)
#define ESTR 66          // embT row stride (halfs): word bank = (id+4q)%32, id-gather clean
#define XSTR 513         // staged x row stride (ints): bank=(r+t)%32, conflict-free
#define HFSTR 132        // final-h fp32 row stride
#define ASCALE 2.8853900817779268f   // 2*log2(e): folds tanh's 2x and log2e mul into A

typedef _Float16 half8  __attribute__((ext_vector_type(8)));
typedef __fp16   fp16x2 __attribute__((ext_vector_type(2)));   // cvt_pkrtz native type
typedef float    floatx4 __attribute__((ext_vector_type(4)));

// acc is pre-scaled by 2*log2e: tanh(x) = 1 - 2/(1+2^(2x*log2e))
__device__ __forceinline__ float tanh_scaled(float z) {
    float e = __builtin_amdgcn_exp2f(z);          // v_exp_f32
    float r = __builtin_amdgcn_rcpf(e + 1.0f);    // v_rcp_f32
    return fmaf(-2.0f, r, 1.0f);
}

__device__ __forceinline__ unsigned pk_u32(fp16x2 v) {
    union { fp16x2 h; unsigned u; } c; c.h = v; return c.u;
}

// (512, 4): 2 blocks/CU * 8 waves = 4 waves/EU -> VGPR cap 128; demand ~88 -> no spill.
__launch_bounds__(NTHR, 4)
__global__ void rnn_mfma_kernel(const int* __restrict__ x,
                                const int* __restrict__ xlen,
                                const float* __restrict__ emb,
                                const float* __restrict__ W_ih,
                                const float* __restrict__ W_hh,
                                const float* __restrict__ b_ih,
                                const float* __restrict__ b_hh,
                                const float* __restrict__ W_out,
                                const float* __restrict__ b_out,
                                float* __restrict__ out)
{
    // Exchange buffers: h-fragment kc for lane l at exB[buf][kc][l] (uint4=half8,
    // k = 32kc+8q+j, batch n; l = 16q+n). Reads: b128 stride-16B, conflict-free.
    // Writes: each wave contributes one uint2 half-slot (its 16 features land
    // in-place thanks to the A-row permutation). Double-buffered: 1 barrier/step.
    __shared__ __align__(16) uint4    exB[2][4][64];
    __shared__ __align__(16) _Float16 sEmb[Vn * ESTR];  // cols 0..19 emb, 20 = 1.0, 21..31 = 0
    __shared__ __align__(16) float    sHf[ROWS * HFSTR];
    __shared__ int   sX[ROWS * XSTR];
    __shared__ float sLogit[ROWS][On];
    __shared__ float sMLS[ROWS];
    __shared__ float sPad[9000];   // 36KB pad: total ~73KB -> exactly 2 blocks/CU

    const int tid  = threadIdx.x;
    // Co-resident blocks must have matched trip counts (lengths sorted desc).
    // Remap so pairs (b, b+256) AND (b, b+-1) both land on adjacent-length groups.
    const int b    = blockIdx.x;
    const int gi   = (b < (NBLK / 2)) ? (2 * b) : (2 * (b - NBLK / 2) + 1);
    const int row0 = gi * ROWS;

    // volatile touch keeps sPad (and the 2-block/CU LDS footprint) alive
    ((volatile float*)sPad)[tid % 9000] = 0.0f;

    const int w    = tid >> 6;       // wave 0..7 -> owns 16 h features (see map below)
    const int lane = tid & 63;
    const int n    = lane & 15;      // MFMA col (batch slot) AND A fragment row m
    const int q    = lane >> 4;      // quad
    const int nr   = n & (ROWS - 1); // clamped batch row for id reads (n>=8 lanes idle)
    const int kcW  = w >> 1;         // which 32-k fragment this wave's output feeds
    const int bsel = w & 1;          // which uint2 half of the 16B slot

    // ---- A operand (static, 20 VGPRs): PERMUTED row map so C output of wave w,
    // lane (q,n), reg i == h feature F = 32*kcW + 8q + 4*bsel + i. The packed
    // tanh output (uint2) is then EXACTLY the right 8B of B-fragment kcW --
    // no cross-lane shuffle, one ds_write_b64 per lane per step.
    //   A row m = lane&15 loads weight row F(m) = 32*kcW + 8*(m>>2) + 4*bsel + (m&3).
    // K order: k<128 W_hh col k; 128..147 W_ih; 148 fused bias (constant-1 xe col).
    // Pre-scaled by 2*log2e (tanh input fusion).
    half8 Ah[KC];
    const int f = 32 * kcW + 8 * (n >> 2) + 4 * bsel + (n & 3);
    #pragma unroll
    for (int kc = 0; kc < 4; ++kc) {
        const float* p = &W_hh[f * Hn + kc * 32 + q * 8];
        #pragma unroll
        for (int i = 0; i < 8; ++i)
            Ah[kc][i] = (_Float16)(p[i] * ASCALE);
    }
    #pragma unroll
    for (int i = 0; i < 8; ++i) {
        int e = q * 8 + i;
        float v = 0.0f;
        if (e < En)       v = W_ih[f * En + e];
        else if (e == 20) v = b_ih[f] + b_hh[f];
        Ah[4][i] = (_Float16)(v * ASCALE);
    }

    // ---- build embT (fp16) with constant-1 bias column (cols 0..31 used)
    for (int idx = tid; idx < Vn * 32; idx += NTHR) {
        int c = idx >> 5, j = idx & 31;
        float v = (j < En) ? emb[c * En + j] : (j == 20 ? 1.0f : 0.0f);
        sEmb[c * ESTR + j] = (_Float16)v;
    }
    // ---- stage vocab ids (int4-vectorized; 512 % 4 == 0 -> no row crossing)
    for (int idx = tid * 4; idx < ROWS * Tn; idx += NTHR * 4) {
        int4 v = *(const int4*)&x[row0 * Tn + idx];
        int r = idx >> 9, t = idx & 511;
        sX[r * XSTR + t]     = v.x;
        sX[r * XSTR + t + 1] = v.y;
        sX[r * XSTR + t + 2] = v.z;
        sX[r * XSTR + t + 3] = v.w;
    }
    // ---- zero both exchange buffers (h0 = 0)
    for (int idx = tid; idx < 2 * 4 * 64; idx += NTHR)
        ((uint4*)exB)[idx] = make_uint4(0u, 0u, 0u, 0u);
    __syncthreads();

    const int Lmax  = xlen[row0];    // sorted descending -> block trip count
    const int len_n = (n < ROWS) ? xlen[row0 + n] : 0;   // n>=8: frozen at h=0

    // ---- xe pipeline: lane (q,n) needs xe cols 8q..8q+7 of token x[nr][t].
    // The xe MFMA partial for step t+1 is pre-accumulated BEFORE the barrier of
    // step t (xe is known ahead), shortening the post-barrier dependent chain.
    int     idN;
    floatx4 P = {0.f, 0.f, 0.f, 0.f};   // A4 . xe(t) partial for the upcoming step
    {
        int id0 = sX[nr * XSTR];
        half8 xe0 = *(const half8*)&sEmb[id0 * ESTR + 8 * q];
        P = __builtin_amdgcn_mfma_f32_16x16x32_f16(Ah[4], xe0, P, 0, 0, 0);
        idN = sX[nr * XSTR + (Lmax > 1 ? 1 : 0)];
    }

    float hreg[4] = {0.f, 0.f, 0.f, 0.f};

    const int wOffH = 32 * kcW + 8 * q + 4 * bsel;   // this lane's feature base

    // one step: read 4 h-frags, 4 MFMA on top of pre-computed xe partial
    // (aE depth 3 incl. P, aO depth 2), tanh+freeze+pack, one uint2 publish,
    // prefetch xe(t+1) partial, ONE barrier. Buffers compile-time (unroll by 2).
    #define RNN_STEP(BR, BW, t)                                                   \
    {                                                                             \
        half8 bf0 = *(const half8*)&exB[BR][0][lane];                             \
        half8 bf1 = *(const half8*)&exB[BR][1][lane];                             \
        half8 bf2 = *(const half8*)&exB[BR][2][lane];                             \
        half8 bf3 = *(const half8*)&exB[BR][3][lane];                             \
        floatx4 aE = P;                                                           \
        floatx4 aO = {0.f, 0.f, 0.f, 0.f};                                        \
        aE = __builtin_amdgcn_mfma_f32_16x16x32_f16(Ah[0], bf0, aE, 0, 0, 0);     \
        aO = __builtin_amdgcn_mfma_f32_16x16x32_f16(Ah[1], bf1, aO, 0, 0, 0);     \
        aE = __builtin_amdgcn_mfma_f32_16x16x32_f16(Ah[2], bf2, aE, 0, 0, 0);     \
        aO = __builtin_amdgcn_mfma_f32_16x16x32_f16(Ah[3], bf3, aO, 0, 0, 0);     \
        const bool upd = ((t) < len_n);                                           \
        _Pragma("unroll")                                                         \
        for (int i = 0; i < 4; ++i) {                                             \
            float v = tanh_scaled(aE[i] + aO[i]);                                 \
            hreg[i] = upd ? v : hreg[i];                                          \
        }                                                                         \
        uint2 pk;                                                                 \
        pk.x = pk_u32(__builtin_amdgcn_cvt_pkrtz(hreg[0], hreg[1]));              \
        pk.y = pk_u32(__builtin_amdgcn_cvt_pkrtz(hreg[2], hreg[3]));              \
        *(uint2*)((_Float16*)&exB[BW][kcW][0] + lane * 8 + 4 * bsel) = pk;        \
        half8 xeN = *(const half8*)&sEmb[idN * ESTR + 8 * q];                     \
        int tn = (t) + 2;                                                         \
        int idN2 = sX[nr * XSTR + (tn < Lmax ? tn : Lmax - 1)];                   \
        floatx4 Pz = {0.f, 0.f, 0.f, 0.f};                                        \
        P = __builtin_amdgcn_mfma_f32_16x16x32_f16(Ah[4], xeN, Pz, 0, 0, 0);      \
        idN = idN2;                                                               \
        __syncthreads();                                                          \
    }

    int t = 0;
    for (; t + 2 <= Lmax; t += 2) {
        RNN_STEP(0, 1, t);
        RNN_STEP(1, 0, t + 1);
    }
    if (t < Lmax) {
        RNN_STEP(0, 1, t);
    }
    #undef RNN_STEP

    // ---- publish final fp32 h: lane (q,n) of wave w holds features wOffH+0..3
    if (n < ROWS) {
        float4 f0;
        f0.x = hreg[0]; f0.y = hreg[1]; f0.z = hreg[2]; f0.w = hreg[3];
        *(float4*)&sHf[n * HFSTR + wOffH] = f0;
    }
    __syncthreads();

    // ---- epilogue: logits = relu(h) @ W_out^T + b_out, then log_softmax
    for (int it = tid; it < ROWS * On; it += NTHR) {
        int r = it / On, c = it % On;
        float acc = b_out[c];
        for (int k = 0; k < Hn; ++k) {
            float hv = sHf[r * HFSTR + k];
            hv = hv > 0.0f ? hv : 0.0f;
            acc = fmaf(hv, W_out[c * Hn + k], acc);
        }
        sLogit[r][c] = acc;
    }
    __syncthreads();

    if (tid < ROWS) {
        float m = -INFINITY;
        #pragma unroll
        for (int c = 0; c < On; ++c) m = fmaxf(m, sLogit[tid][c]);
        float s = 0.0f;
        #pragma unroll
        for (int c = 0; c < On; ++c) s += __expf(sLogit[tid][c] - m);
        sMLS[tid] = m + __logf(s);
    }
    __syncthreads();

    for (int it = tid; it < ROWS * On; it += NTHR) {
        int r = it / On, c = it % On;
        out[(row0 + r) * On + c] = sLogit[r][c] - sMLS[r];
    }
}

extern "C" void kernel_launch(void* const* d_in, const int* in_sizes, int n_in,
                              void* d_out, int out_size, void* d_ws, size_t ws_size,
                              hipStream_t stream) {
    const int*   x     = (const int*)d_in[0];
    const int*   xlen  = (const int*)d_in[1];
    const float* emb   = (const float*)d_in[2];
    const float* W_ih  = (const float*)d_in[3];
    const float* W_hh  = (const float*)d_in[4];
    const float* b_ih  = (const float*)d_in[5];
    const float* b_hh  = (const float*)d_in[6];
    const float* W_out = (const float*)d_in[7];
    const float* b_out = (const float*)d_in[8];
    float*       out   = (float*)d_out;

    rnn_mfma_kernel<<<NBLK, NTHR, 0, stream>>>(x, xlen, emb, W_ih, W_hh,
                                               b_ih, b_hh, W_out, b_out, out);
}